// Round 9
// baseline (73.746 us; speedup 1.0000x reference)
//
#include <hip/hip_runtime.h>

#define N_DRUG 50000
#define F_DRUG 256
#define E_DRUG 1000000
#define N_DIS  20000
#define F_DIS  128
#define E_DIS  640000
#define NHID   64

#define NBKT  512          // padded LDS bucket-hist size (actual 391 / 313)
#define SH1   7
#define ROWS1 128
#define NBB1  391          // ceil(N_DRUG/128)
#define CAPB1 3072         // 6*512; mean 2560, +10 sigma
#define SH2   6
#define ROWS2 64
#define NBB2  313          // ceil(N_DIS/64)
#define CAPB2 2560         // 5*512; mean 2048, +11 sigma

#define BINCH 4096         // edges per bin block
#define NCH1  245          // ceil(E_DRUG/4096)
#define NCH2  157          // ceil(E_DIS/4096)

#define NBG1  391          // gemm blocks drug (128 rows each)
#define NBG2  157          // gemm blocks dis

#define NP1   950          // phase1 grid = NCH1+NCH2+NBG1+NBG2
#define NP2   704          // phase2 grid = NBB1+NBB2

typedef __bf16 bf16x8 __attribute__((ext_vector_type(8)));
typedef float  f32x4  __attribute__((ext_vector_type(4)));

__device__ inline float bfl(unsigned u) {
    union { unsigned i; float f; } c; c.i = u << 16; return c.f;
}
__device__ inline float bfh(unsigned u) {
    union { unsigned i; float f; } c; c.i = u & 0xffff0000u; return c.f;
}

// ---------------- phase 1: bin + MFMA GEMM, roles interleaved across CUs ----------------
__global__ void __launch_bounds__(256)
phase1_kernel(const int* __restrict__ ei1, int* __restrict__ gcur1, unsigned* __restrict__ bin1,
              const int* __restrict__ ei2, int* __restrict__ gcur2, unsigned* __restrict__ bin2,
              const float* __restrict__ x1, const float* __restrict__ W1, __bf16* __restrict__ h1,
              const float* __restrict__ x2, const float* __restrict__ W2, __bf16* __restrict__ h2) {
    __shared__ int smem[8192];   // 32 KB, role-dependent layout
    // coprime remap interleaves bin-role and gemm-role blocks across CUs
    const int bid = (int)(((long long)blockIdx.x * 401) % NP1);
    const int tid = threadIdx.x;

    if (bid < NCH1 + NCH2) {
        // ---------------- bin role ----------------
        const int* ei; int* gcur; unsigned* binned; int E, shift, capb, cb;
        if (bid < NCH1) {
            ei = ei1; gcur = gcur1; binned = bin1; E = E_DRUG; shift = SH1; capb = CAPB1; cb = bid;
        } else {
            ei = ei2; gcur = gcur2; binned = bin2; E = E_DIS; shift = SH2; capb = CAPB2; cb = bid - NCH1;
        }
        int* hist  = smem;          // 512
        int* excl  = smem + 512;    // 512
        int* gbase = smem + 1024;   // 512
        int* buf   = smem + 1536;   // 4096

        const int base = cb * BINCH;
        const int total = min(BINCH, E - base);

        for (int i = tid; i < NBKT; i += 256) hist[i] = 0;
        __syncthreads();

        unsigned my[16]; int mybkt[16]; int myloc[16];
#pragma unroll
        for (int j = 0; j < 16; ++j) {
            int e = base + j * 256 + tid;
            if (e < E) {
                int s = ei[e];
                int d = ei[E + e];
                my[j] = ((unsigned)s << 16) | (unsigned)d;
                mybkt[j] = d >> shift;
                myloc[j] = atomicAdd(&hist[mybkt[j]], 1);
            } else {
                mybkt[j] = -1;
            }
        }
        __syncthreads();

        if (tid < 64) {
            int run = 0;
            for (int ch = 0; ch < NBKT / 64; ++ch) {
                int v = hist[ch * 64 + tid];
                int incl = v;
#pragma unroll
                for (int off = 1; off < 64; off <<= 1) {
                    int t = __shfl_up(incl, off);
                    if (tid >= off) incl += t;
                }
                excl[ch * 64 + tid] = run + incl - v;
                run += __shfl(incl, 63);
            }
        }
        __syncthreads();

        for (int i = tid; i < NBKT; i += 256) {
            int c = hist[i];
            if (c) gbase[i] = atomicAdd(&gcur[i], c);
        }
        __syncthreads();

#pragma unroll
        for (int j = 0; j < 16; ++j)
            if (mybkt[j] >= 0) buf[excl[mybkt[j]] + myloc[j]] = (int)my[j];
        __syncthreads();

        for (int s = tid; s < total; s += 256) {
            unsigned p = (unsigned)buf[s];
            int b = (int)(p & 0xFFFFu) >> shift;
            int idx = gbase[b] + (s - excl[b]);
            if (idx < capb)                       // overflow guard (statistically unreachable)
                binned[(size_t)b * capb + idx] = p;
        }
    } else {
        // ---------------- gemm role ----------------
        __bf16* Wlds = (__bf16*)smem;             // up to 256*64 bf16 = 32 KB
        const float* x; const float* W; __bf16* h; int M, K, lb;
        int gb = bid - (NCH1 + NCH2);
        if (gb < NBG1) {
            x = x1; W = W1; h = h1; M = N_DRUG; K = F_DRUG; lb = gb;
        } else {
            x = x2; W = W2; h = h2; M = N_DIS; K = F_DIS; lb = gb - NBG1;
        }

        for (int idx = tid; idx < K * 64; idx += 256) {
            int k = idx >> 6, col = idx & 63;
            Wlds[((k >> 3) * 64 + col) * 8 + (k & 7)] = (__bf16)W[idx];
        }
        __syncthreads();

        const int wid = tid >> 6, lane = tid & 63;
        const int l15 = lane & 15, lhi = lane >> 4;
        const int r0 = lb * 128 + wid * 32;
        if (r0 >= M) return;

        f32x4 acc[2][4];
#pragma unroll
        for (int m = 0; m < 2; ++m)
#pragma unroll
            for (int c = 0; c < 4; ++c) acc[m][c] = {0.f, 0.f, 0.f, 0.f};

        int rowA0 = r0 + l15;
        int rowA1 = r0 + 16 + l15;
        int cr0 = rowA0 < M ? rowA0 : M - 1;
        int cr1 = rowA1 < M ? rowA1 : M - 1;
        const float* pA0 = x + (size_t)cr0 * K + lhi * 8;
        const float* pA1 = x + (size_t)cr1 * K + lhi * 8;
        const bf16x8* Wv = (const bf16x8*)Wlds;

        for (int kk = 0; kk < K; kk += 32) {
            float4 a0l = *(const float4*)(pA0 + kk);
            float4 a0h = *(const float4*)(pA0 + kk + 4);
            float4 a1l = *(const float4*)(pA1 + kk);
            float4 a1h = *(const float4*)(pA1 + kk + 4);
            bf16x8 af0, af1;
            af0[0] = (__bf16)a0l.x; af0[1] = (__bf16)a0l.y;
            af0[2] = (__bf16)a0l.z; af0[3] = (__bf16)a0l.w;
            af0[4] = (__bf16)a0h.x; af0[5] = (__bf16)a0h.y;
            af0[6] = (__bf16)a0h.z; af0[7] = (__bf16)a0h.w;
            af1[0] = (__bf16)a1l.x; af1[1] = (__bf16)a1l.y;
            af1[2] = (__bf16)a1l.z; af1[3] = (__bf16)a1l.w;
            af1[4] = (__bf16)a1h.x; af1[5] = (__bf16)a1h.y;
            af1[6] = (__bf16)a1h.z; af1[7] = (__bf16)a1h.w;
            const int kblk = (kk >> 3) + lhi;
#pragma unroll
            for (int c = 0; c < 4; ++c) {
                bf16x8 bf = Wv[kblk * 64 + c * 16 + l15];
                acc[0][c] = __builtin_amdgcn_mfma_f32_16x16x32_bf16(af0, bf, acc[0][c], 0, 0, 0);
                acc[1][c] = __builtin_amdgcn_mfma_f32_16x16x32_bf16(af1, bf, acc[1][c], 0, 0, 0);
            }
        }

#pragma unroll
        for (int m = 0; m < 2; ++m) {
            int rbase = r0 + m * 16 + lhi * 4;
#pragma unroll
            for (int c = 0; c < 4; ++c) {
                int col = c * 16 + l15;
#pragma unroll
                for (int r = 0; r < 4; ++r) {
                    int row = rbase + r;
                    if (row < M) h[(size_t)row * 64 + col] = (__bf16)acc[m][c][r];
                }
            }
        }
    }
}

// ---------------- phase 2: fused per-bucket sort + uint4 gather ----------------
// 512 threads = 8 waves per bucket; drug/dis buckets interleaved across CUs.
// Packed bins read once into 6 regs/thread; LDS CSR (int atomics); gather with
// lane = (group g = lane>>3, 8 edges/wave-load) x (feature octet q = lane&7).
__global__ void __launch_bounds__(512)
sortgather_kernel(const unsigned* __restrict__ bin1, const int* __restrict__ gc1,
                  const unsigned short* __restrict__ h1, const float* __restrict__ bias1,
                  float* __restrict__ out1,
                  const unsigned* __restrict__ bin2, const int* __restrict__ gc2,
                  const unsigned short* __restrict__ h2, const float* __restrict__ bias2,
                  float* __restrict__ out2) {
    __shared__ int hist[ROWS1];
    __shared__ int nstart[ROWS1 + 1];
    __shared__ int cur[ROWS1];
    __shared__ int srcbuf[CAPB1];

    // coprime remap interleaves heavy drug buckets with lighter dis buckets
    const int bm = (int)(((long long)blockIdx.x * 313) % NP2);

    const unsigned* pb; const unsigned short* hbf; const float* bias; float* out;
    int N, b, rows, capb, cnt;
    if (bm < NBB1) {
        b = bm;
        pb = bin1 + (size_t)b * CAPB1; hbf = h1; bias = bias1; out = out1;
        N = N_DRUG; rows = ROWS1; capb = CAPB1;
        cnt = gc1[b];
    } else {
        b = bm - NBB1;
        pb = bin2 + (size_t)b * CAPB2; hbf = h2; bias = bias2; out = out2;
        N = N_DIS; rows = ROWS2; capb = CAPB2;
        cnt = gc2[b];
    }
    cnt = min(cnt, capb);

    const int tid = threadIdx.x;
    const int lane = tid & 63, w = tid >> 6;
    const int mask = rows - 1;

    for (int i = tid; i < rows; i += 512) hist[i] = 0;
    __syncthreads();

    // single global read of the bucket run into registers
    unsigned pv[6];
#pragma unroll
    for (int j = 0; j < 6; ++j) {
        int i = j * 512 + tid;
        pv[j] = (i < cnt) ? pb[i] : 0xFFFFFFFFu;
    }

    // pass 1: per-node histogram
#pragma unroll
    for (int j = 0; j < 6; ++j)
        if (pv[j] != 0xFFFFFFFFu) atomicAdd(&hist[(int)(pv[j] & (unsigned)mask)], 1);
    __syncthreads();

    // exclusive scan by wave 0
    if (tid < 64) {
        int run = 0;
        for (int ch = 0; ch * 64 < rows; ++ch) {
            int v = hist[ch * 64 + tid];
            int incl = v;
#pragma unroll
            for (int off = 1; off < 64; off <<= 1) {
                int t = __shfl_up(incl, off);
                if (tid >= off) incl += t;
            }
            nstart[ch * 64 + tid] = run + incl - v;
            run += __shfl(incl, 63);
        }
        if (tid == 0) nstart[rows] = run;
    }
    __syncthreads();
    for (int i = tid; i < rows; i += 512) cur[i] = nstart[i];
    __syncthreads();

    // pass 2: scatter src ids into node-sorted LDS order
#pragma unroll
    for (int j = 0; j < 6; ++j)
        if (pv[j] != 0xFFFFFFFFu) {
            int pos = atomicAdd(&cur[(int)(pv[j] & (unsigned)mask)], 1);
            srcbuf[pos] = (int)(pv[j] >> 16);
        }
    __syncthreads();

    // gather: wave per node; 8 groups x 8-feature octets; uint4 = 8 bf16/lane.
    const int q = lane & 7, g = lane >> 3;
    const float4 bva = *(const float4*)(bias + (q << 3));
    const float4 bvb = *(const float4*)(bias + (q << 3) + 4);
    const int rowbase = b * rows;
    for (int n = w; n < rows; n += 8) {
        int row = rowbase + n;
        int j0 = nstart[n], j1 = nstart[n + 1];
        float a0 = 0.f, a1 = 0.f, a2 = 0.f, a3 = 0.f;
        float a4 = 0.f, a5 = 0.f, a6 = 0.f, a7 = 0.f;
        float c0 = 0.f, c1 = 0.f, c2 = 0.f, c3 = 0.f;
        float c4 = 0.f, c5 = 0.f, c6 = 0.f, c7 = 0.f;
        int j = j0 + g;
        for (; j + 8 < j1; j += 16) {
            int s0 = srcbuf[j];
            int s1 = srcbuf[j + 8];
            uint4 u0 = *(const uint4*)(hbf + ((size_t)s0 << 6) + (q << 3));
            uint4 u1 = *(const uint4*)(hbf + ((size_t)s1 << 6) + (q << 3));
            a0 += bfl(u0.x); a1 += bfh(u0.x); a2 += bfl(u0.y); a3 += bfh(u0.y);
            a4 += bfl(u0.z); a5 += bfh(u0.z); a6 += bfl(u0.w); a7 += bfh(u0.w);
            c0 += bfl(u1.x); c1 += bfh(u1.x); c2 += bfl(u1.y); c3 += bfh(u1.y);
            c4 += bfl(u1.z); c5 += bfh(u1.z); c6 += bfl(u1.w); c7 += bfh(u1.w);
        }
        if (j < j1) {
            int s0 = srcbuf[j];
            uint4 u0 = *(const uint4*)(hbf + ((size_t)s0 << 6) + (q << 3));
            a0 += bfl(u0.x); a1 += bfh(u0.x); a2 += bfl(u0.y); a3 += bfh(u0.y);
            a4 += bfl(u0.z); a5 += bfh(u0.z); a6 += bfl(u0.w); a7 += bfh(u0.w);
        }
        a0 += c0; a1 += c1; a2 += c2; a3 += c3;
        a4 += c4; a5 += c5; a6 += c6; a7 += c7;
#pragma unroll
        for (int off = 8; off < 64; off <<= 1) {
            a0 += __shfl_xor(a0, off); a1 += __shfl_xor(a1, off);
            a2 += __shfl_xor(a2, off); a3 += __shfl_xor(a3, off);
            a4 += __shfl_xor(a4, off); a5 += __shfl_xor(a5, off);
            a6 += __shfl_xor(a6, off); a7 += __shfl_xor(a7, off);
        }
        if (g == 0 && row < N) {
            float4 o1 = make_float4(a0 + bva.x, a1 + bva.y, a2 + bva.z, a3 + bva.w);
            float4 o2 = make_float4(a4 + bvb.x, a5 + bvb.y, a6 + bvb.z, a7 + bvb.w);
            *(float4*)(out + (size_t)row * 64 + (q << 3)) = o1;
            *(float4*)(out + (size_t)row * 64 + (q << 3) + 4) = o2;
        }
    }
}

extern "C" void kernel_launch(void* const* d_in, const int* in_sizes, int n_in,
                              void* d_out, int out_size, void* d_ws, size_t ws_size,
                              hipStream_t stream) {
    const float* drug_x = (const float*)d_in[0];
    const float* dis_x  = (const float*)d_in[1];
    const float* W1     = (const float*)d_in[2];
    const float* b1     = (const float*)d_in[3];
    const float* W2     = (const float*)d_in[4];
    const float* b2     = (const float*)d_in[5];
    const int*   ei1    = (const int*)d_in[6];
    const int*   ei2    = (const int*)d_in[7];
    float* out = (float*)d_out;

    // workspace layout (16B-aligned chunks), ~17 MB total
    char* p = (char*)d_ws;
    __bf16* h1 = (__bf16*)p;    p += (size_t)N_DRUG * NHID * 2;
    __bf16* h2 = (__bf16*)p;    p += (size_t)N_DIS  * NHID * 2;
    int* gcur1 = (int*)p;       p += 392 * 4;                    // 392 = NBB1 padded
    int* gcur2 = (int*)p;       p += 316 * 4;                    // 316 = NBB2 padded
    unsigned* bin1 = (unsigned*)p;  p += (size_t)NBB1 * CAPB1 * 4;
    unsigned* bin2 = (unsigned*)p;  /* p += NBB2 * CAPB2 * 4 */

    // 1) zero bucket cursors (contiguous region, single async DMA — no kernel launch)
    hipMemsetAsync(gcur1, 0, (392 + 316) * sizeof(int), stream);
    // 2) fused bin + GEMM (roles interleaved across CUs)
    phase1_kernel<<<NP1, 256, 0, stream>>>(
        ei1, gcur1, bin1, ei2, gcur2, bin2,
        drug_x, W1, h1, dis_x, W2, h2);
    // 3) fused per-bucket sort + gather (+bias), drug/dis interleaved
    sortgather_kernel<<<NP2, 512, 0, stream>>>(
        bin1, gcur1, (const unsigned short*)h1, b1, out,
        bin2, gcur2, (const unsigned short*)h2, b2, out + (size_t)N_DRUG * NHID);
}

// Round 10
// 65.265 us; speedup vs baseline: 1.1300x; 1.1300x over previous
//
#include <hip/hip_runtime.h>

#define N_DRUG 50000
#define F_DRUG 256
#define E_DRUG 1000000
#define N_DIS  20000
#define F_DIS  128
#define E_DIS  640000
#define NHID   64

#define NBKT  512          // padded LDS bucket-hist size (actual 391 / 313)
#define SH1   7
#define ROWS1 128
#define NBB1  391          // ceil(N_DRUG/128)
#define CAPB1 3072         // 6*512; mean 2560, +10 sigma
#define SH2   6
#define ROWS2 64
#define NBB2  313          // ceil(N_DIS/64)
#define CAPB2 2560         // 5*512; mean 2048, +11 sigma

#define BINCH 4096         // edges per bin block
#define NCH1  245          // ceil(E_DRUG/4096)
#define NCH2  157          // ceil(E_DIS/4096)

#define NBG1  391          // gemm blocks drug (128 rows each)
#define NBG2  157          // gemm blocks dis

#define NP1   950          // phase1 grid = NCH1+NCH2+NBG1+NBG2
#define NP2   704          // phase2 grid = NBB1+NBB2

typedef __bf16 bf16x8 __attribute__((ext_vector_type(8)));
typedef float  f32x4  __attribute__((ext_vector_type(4)));

__device__ inline float bfl(unsigned u) {
    union { unsigned i; float f; } c; c.i = u << 16; return c.f;
}
__device__ inline float bfh(unsigned u) {
    union { unsigned i; float f; } c; c.i = u & 0xffff0000u; return c.f;
}

// ---------------- phase 1: bin (blocks [0,402)) + MFMA GEMM (blocks [402,950)) ----------------
__global__ void __launch_bounds__(256)
phase1_kernel(const int* __restrict__ ei1, int* __restrict__ gcur1, unsigned* __restrict__ bin1,
              const int* __restrict__ ei2, int* __restrict__ gcur2, unsigned* __restrict__ bin2,
              const float* __restrict__ x1, const float* __restrict__ W1, __bf16* __restrict__ h1,
              const float* __restrict__ x2, const float* __restrict__ W2, __bf16* __restrict__ h2) {
    __shared__ int smem[8192];   // 32 KB, role-dependent layout
    const int bid = blockIdx.x;
    const int tid = threadIdx.x;

    if (bid < NCH1 + NCH2) {
        // ---------------- bin role ----------------
        const int* ei; int* gcur; unsigned* binned; int E, shift, capb, cb;
        if (bid < NCH1) {
            ei = ei1; gcur = gcur1; binned = bin1; E = E_DRUG; shift = SH1; capb = CAPB1; cb = bid;
        } else {
            ei = ei2; gcur = gcur2; binned = bin2; E = E_DIS; shift = SH2; capb = CAPB2; cb = bid - NCH1;
        }
        int* hist  = smem;          // 512
        int* excl  = smem + 512;    // 512
        int* gbase = smem + 1024;   // 512
        int* buf   = smem + 1536;   // 4096

        const int base = cb * BINCH;
        const int total = min(BINCH, E - base);

        for (int i = tid; i < NBKT; i += 256) hist[i] = 0;
        __syncthreads();

        unsigned my[16]; int mybkt[16]; int myloc[16];
#pragma unroll
        for (int j = 0; j < 16; ++j) {
            int e = base + j * 256 + tid;
            if (e < E) {
                int s = ei[e];
                int d = ei[E + e];
                my[j] = ((unsigned)s << 16) | (unsigned)d;
                mybkt[j] = d >> shift;
                myloc[j] = atomicAdd(&hist[mybkt[j]], 1);
            } else {
                mybkt[j] = -1;
            }
        }
        __syncthreads();

        if (tid < 64) {
            int run = 0;
            for (int ch = 0; ch < NBKT / 64; ++ch) {
                int v = hist[ch * 64 + tid];
                int incl = v;
#pragma unroll
                for (int off = 1; off < 64; off <<= 1) {
                    int t = __shfl_up(incl, off);
                    if (tid >= off) incl += t;
                }
                excl[ch * 64 + tid] = run + incl - v;
                run += __shfl(incl, 63);
            }
        }
        __syncthreads();

        for (int i = tid; i < NBKT; i += 256) {
            int c = hist[i];
            if (c) gbase[i] = atomicAdd(&gcur[i], c);
        }
        __syncthreads();

#pragma unroll
        for (int j = 0; j < 16; ++j)
            if (mybkt[j] >= 0) buf[excl[mybkt[j]] + myloc[j]] = (int)my[j];
        __syncthreads();

        for (int s = tid; s < total; s += 256) {
            unsigned p = (unsigned)buf[s];
            int b = (int)(p & 0xFFFFu) >> shift;
            int idx = gbase[b] + (s - excl[b]);
            if (idx < capb)                       // overflow guard (statistically unreachable)
                binned[(size_t)b * capb + idx] = p;
        }
    } else {
        // ---------------- gemm role ----------------
        __bf16* Wlds = (__bf16*)smem;             // up to 256*64 bf16 = 32 KB
        const float* x; const float* W; __bf16* h; int M, K, lb;
        int gb = bid - (NCH1 + NCH2);
        if (gb < NBG1) {
            x = x1; W = W1; h = h1; M = N_DRUG; K = F_DRUG; lb = gb;
        } else {
            x = x2; W = W2; h = h2; M = N_DIS; K = F_DIS; lb = gb - NBG1;
        }

        for (int idx = tid; idx < K * 64; idx += 256) {
            int k = idx >> 6, col = idx & 63;
            Wlds[((k >> 3) * 64 + col) * 8 + (k & 7)] = (__bf16)W[idx];
        }
        __syncthreads();

        const int wid = tid >> 6, lane = tid & 63;
        const int l15 = lane & 15, lhi = lane >> 4;
        const int r0 = lb * 128 + wid * 32;
        if (r0 >= M) return;

        f32x4 acc[2][4];
#pragma unroll
        for (int m = 0; m < 2; ++m)
#pragma unroll
            for (int c = 0; c < 4; ++c) acc[m][c] = {0.f, 0.f, 0.f, 0.f};

        int rowA0 = r0 + l15;
        int rowA1 = r0 + 16 + l15;
        int cr0 = rowA0 < M ? rowA0 : M - 1;
        int cr1 = rowA1 < M ? rowA1 : M - 1;
        const float* pA0 = x + (size_t)cr0 * K + lhi * 8;
        const float* pA1 = x + (size_t)cr1 * K + lhi * 8;
        const bf16x8* Wv = (const bf16x8*)Wlds;

        for (int kk = 0; kk < K; kk += 32) {
            float4 a0l = *(const float4*)(pA0 + kk);
            float4 a0h = *(const float4*)(pA0 + kk + 4);
            float4 a1l = *(const float4*)(pA1 + kk);
            float4 a1h = *(const float4*)(pA1 + kk + 4);
            bf16x8 af0, af1;
            af0[0] = (__bf16)a0l.x; af0[1] = (__bf16)a0l.y;
            af0[2] = (__bf16)a0l.z; af0[3] = (__bf16)a0l.w;
            af0[4] = (__bf16)a0h.x; af0[5] = (__bf16)a0h.y;
            af0[6] = (__bf16)a0h.z; af0[7] = (__bf16)a0h.w;
            af1[0] = (__bf16)a1l.x; af1[1] = (__bf16)a1l.y;
            af1[2] = (__bf16)a1l.z; af1[3] = (__bf16)a1l.w;
            af1[4] = (__bf16)a1h.x; af1[5] = (__bf16)a1h.y;
            af1[6] = (__bf16)a1h.z; af1[7] = (__bf16)a1h.w;
            const int kblk = (kk >> 3) + lhi;
#pragma unroll
            for (int c = 0; c < 4; ++c) {
                bf16x8 bf = Wv[kblk * 64 + c * 16 + l15];
                acc[0][c] = __builtin_amdgcn_mfma_f32_16x16x32_bf16(af0, bf, acc[0][c], 0, 0, 0);
                acc[1][c] = __builtin_amdgcn_mfma_f32_16x16x32_bf16(af1, bf, acc[1][c], 0, 0, 0);
            }
        }

#pragma unroll
        for (int m = 0; m < 2; ++m) {
            int rbase = r0 + m * 16 + lhi * 4;
#pragma unroll
            for (int c = 0; c < 4; ++c) {
                int col = c * 16 + l15;
#pragma unroll
                for (int r = 0; r < 4; ++r) {
                    int row = rbase + r;
                    if (row < M) h[(size_t)row * 64 + col] = (__bf16)acc[m][c][r];
                }
            }
        }
    }
}

// ---------------- phase 2: fused per-bucket sort + 4-edge-per-load gather ----------------
// 512 threads = 8 waves per bucket. Packed bins read once into 6 regs/thread;
// LDS CSR (int atomics); gather lane = (group g = lane>>4) x (feature quad q = lane&15),
// 4 independent uint2 loads in flight per group (16 edges/wave per iteration).
__global__ void __launch_bounds__(512)
sortgather_kernel(const unsigned* __restrict__ bin1, const int* __restrict__ gc1,
                  const unsigned short* __restrict__ h1, const float* __restrict__ bias1,
                  float* __restrict__ out1,
                  const unsigned* __restrict__ bin2, const int* __restrict__ gc2,
                  const unsigned short* __restrict__ h2, const float* __restrict__ bias2,
                  float* __restrict__ out2) {
    __shared__ int hist[ROWS1];
    __shared__ int nstart[ROWS1 + 1];
    __shared__ int cur[ROWS1];
    __shared__ int srcbuf[CAPB1];

    const unsigned* pb; const unsigned short* hbf; const float* bias; float* out;
    int N, b, rows, capb, cnt;
    if ((int)blockIdx.x < NBB1) {
        b = blockIdx.x;
        pb = bin1 + (size_t)b * CAPB1; hbf = h1; bias = bias1; out = out1;
        N = N_DRUG; rows = ROWS1; capb = CAPB1;
        cnt = gc1[b];
    } else {
        b = blockIdx.x - NBB1;
        pb = bin2 + (size_t)b * CAPB2; hbf = h2; bias = bias2; out = out2;
        N = N_DIS; rows = ROWS2; capb = CAPB2;
        cnt = gc2[b];
    }
    cnt = min(cnt, capb);

    const int tid = threadIdx.x;
    const int lane = tid & 63, w = tid >> 6;
    const int mask = rows - 1;

    for (int i = tid; i < rows; i += 512) hist[i] = 0;
    __syncthreads();

    // single global read of the bucket run into registers
    unsigned pv[6];
#pragma unroll
    for (int j = 0; j < 6; ++j) {
        int i = j * 512 + tid;
        pv[j] = (i < cnt) ? pb[i] : 0xFFFFFFFFu;
    }

    // pass 1: per-node histogram
#pragma unroll
    for (int j = 0; j < 6; ++j)
        if (pv[j] != 0xFFFFFFFFu) atomicAdd(&hist[(int)(pv[j] & (unsigned)mask)], 1);
    __syncthreads();

    // exclusive scan by wave 0
    if (tid < 64) {
        int run = 0;
        for (int ch = 0; ch * 64 < rows; ++ch) {
            int v = hist[ch * 64 + tid];
            int incl = v;
#pragma unroll
            for (int off = 1; off < 64; off <<= 1) {
                int t = __shfl_up(incl, off);
                if (tid >= off) incl += t;
            }
            nstart[ch * 64 + tid] = run + incl - v;
            run += __shfl(incl, 63);
        }
        if (tid == 0) nstart[rows] = run;
    }
    __syncthreads();
    for (int i = tid; i < rows; i += 512) cur[i] = nstart[i];
    __syncthreads();

    // pass 2: scatter src ids into node-sorted LDS order
#pragma unroll
    for (int j = 0; j < 6; ++j)
        if (pv[j] != 0xFFFFFFFFu) {
            int pos = atomicAdd(&cur[(int)(pv[j] & (unsigned)mask)], 1);
            srcbuf[pos] = (int)(pv[j] >> 16);
        }
    __syncthreads();

    // gather: wave per node; group g handles every 4th edge; lane owns 4 features.
    const int q = lane & 15, g = lane >> 4;
    const float4 bv = *(const float4*)(bias + (q << 2));
    const int rowbase = b * rows;
    for (int n = w; n < rows; n += 8) {
        int row = rowbase + n;
        int j0 = nstart[n], j1 = nstart[n + 1];
        float ax0 = 0.f, ay0 = 0.f, az0 = 0.f, aw0 = 0.f;
        float ax1 = 0.f, ay1 = 0.f, az1 = 0.f, aw1 = 0.f;
        float ax2 = 0.f, ay2 = 0.f, az2 = 0.f, aw2 = 0.f;
        float ax3 = 0.f, ay3 = 0.f, az3 = 0.f, aw3 = 0.f;
        int j = j0 + g;
        // 4 independent loads in flight per iteration (16 edges/wave)
        for (; j + 12 < j1; j += 16) {
            int s0 = srcbuf[j];
            int s1 = srcbuf[j + 4];
            int s2 = srcbuf[j + 8];
            int s3 = srcbuf[j + 12];
            uint2 u0 = *(const uint2*)(hbf + ((size_t)s0 << 6) + (q << 2));
            uint2 u1 = *(const uint2*)(hbf + ((size_t)s1 << 6) + (q << 2));
            uint2 u2 = *(const uint2*)(hbf + ((size_t)s2 << 6) + (q << 2));
            uint2 u3 = *(const uint2*)(hbf + ((size_t)s3 << 6) + (q << 2));
            ax0 += bfl(u0.x); ay0 += bfh(u0.x); az0 += bfl(u0.y); aw0 += bfh(u0.y);
            ax1 += bfl(u1.x); ay1 += bfh(u1.x); az1 += bfl(u1.y); aw1 += bfh(u1.y);
            ax2 += bfl(u2.x); ay2 += bfh(u2.x); az2 += bfl(u2.y); aw2 += bfh(u2.y);
            ax3 += bfl(u3.x); ay3 += bfh(u3.x); az3 += bfl(u3.y); aw3 += bfh(u3.y);
        }
        for (; j < j1; j += 4) {
            int s0 = srcbuf[j];
            uint2 u0 = *(const uint2*)(hbf + ((size_t)s0 << 6) + (q << 2));
            ax0 += bfl(u0.x); ay0 += bfh(u0.x); az0 += bfl(u0.y); aw0 += bfh(u0.y);
        }
        float fx = (ax0 + ax1) + (ax2 + ax3);
        float fy = (ay0 + ay1) + (ay2 + ay3);
        float fz = (az0 + az1) + (az2 + az3);
        float fw = (aw0 + aw1) + (aw2 + aw3);
        fx += __shfl_xor(fx, 16); fy += __shfl_xor(fy, 16);
        fz += __shfl_xor(fz, 16); fw += __shfl_xor(fw, 16);
        fx += __shfl_xor(fx, 32); fy += __shfl_xor(fy, 32);
        fz += __shfl_xor(fz, 32); fw += __shfl_xor(fw, 32);
        if (g == 0 && row < N) {
            float4 o = make_float4(fx + bv.x, fy + bv.y, fz + bv.z, fw + bv.w);
            *(float4*)(out + (size_t)row * 64 + (q << 2)) = o;
        }
    }
}

extern "C" void kernel_launch(void* const* d_in, const int* in_sizes, int n_in,
                              void* d_out, int out_size, void* d_ws, size_t ws_size,
                              hipStream_t stream) {
    const float* drug_x = (const float*)d_in[0];
    const float* dis_x  = (const float*)d_in[1];
    const float* W1     = (const float*)d_in[2];
    const float* b1     = (const float*)d_in[3];
    const float* W2     = (const float*)d_in[4];
    const float* b2     = (const float*)d_in[5];
    const int*   ei1    = (const int*)d_in[6];
    const int*   ei2    = (const int*)d_in[7];
    float* out = (float*)d_out;

    // workspace layout (16B-aligned chunks), ~17 MB total
    char* p = (char*)d_ws;
    __bf16* h1 = (__bf16*)p;    p += (size_t)N_DRUG * NHID * 2;
    __bf16* h2 = (__bf16*)p;    p += (size_t)N_DIS  * NHID * 2;
    int* gcur1 = (int*)p;       p += 392 * 4;                    // NBB1 padded
    int* gcur2 = (int*)p;       p += 316 * 4;                    // NBB2 padded
    unsigned* bin1 = (unsigned*)p;  p += (size_t)NBB1 * CAPB1 * 4;
    unsigned* bin2 = (unsigned*)p;  /* p += NBB2 * CAPB2 * 4 */

    // 1) zero bucket cursors (contiguous region, single async DMA — no kernel launch)
    hipMemsetAsync(gcur1, 0, (392 + 316) * sizeof(int), stream);
    // 2) fused bin + GEMM (independent work, concurrent block roles)
    phase1_kernel<<<NP1, 256, 0, stream>>>(
        ei1, gcur1, bin1, ei2, gcur2, bin2,
        drug_x, W1, h1, dis_x, W2, h2);
    // 3) fused per-bucket sort + gather (+bias), both graphs
    sortgather_kernel<<<NP2, 512, 0, stream>>>(
        bin1, gcur1, (const unsigned short*)h1, b1, out,
        bin2, gcur2, (const unsigned short*)h2, b2, out + (size_t)N_DRUG * NHID);
}